// Round 1
// baseline (1292.267 us; speedup 1.0000x reference)
//
#include <hip/hip_runtime.h>
#include <math.h>

#define N_NODES 50000
#define E_EDGES 1600000
#define IN_DIM 128
#define HEADS 4
#define OUT_DIM 32
#define HF 128            // HEADS*OUT_DIM
#define NEG_SLOPE 0.2f

// ---------------------------------------------------------------------------
// Kernel A: Wh = x @ W  (N x 128 @ 128 x 128), fused per-node attention halves
//   a_src[n,h] = sum_f Wh[n,h,f] * att[h,f]
//   a_dst[n,h] = sum_f Wh[n,h,f] * att[h,OUT_DIM+f]
// Block: 256 threads, 32 rows per block. W (64KB) + x-tile (16KB) in LDS.
// ---------------------------------------------------------------------------
__global__ __launch_bounds__(256) void gat_proj(
        const float* __restrict__ x, const float* __restrict__ W,
        const float* __restrict__ att, float* __restrict__ Wh,
        float* __restrict__ a_src, float* __restrict__ a_dst) {
    __shared__ float Ws[IN_DIM][HF];          // 64 KB
    __shared__ float xs[32][IN_DIM];          // 16 KB
    __shared__ float atts[HEADS][2 * OUT_DIM];

    const int tid = threadIdx.x;

    // Stage W (16384 floats) as float4, coalesced.
    const float4* W4 = (const float4*)W;
    float4* Ws4 = (float4*)&Ws[0][0];
    for (int i = tid; i < IN_DIM * HF / 4; i += 256) Ws4[i] = W4[i];
    if (tid < HEADS * 2 * OUT_DIM / 4)
        ((float4*)&atts[0][0])[tid] = ((const float4*)att)[tid];

    const int rowBase = blockIdx.x * 32;
    const int rowsHere = min(32, N_NODES - rowBase);
    const float4* x4 = (const float4*)(x + (size_t)rowBase * IN_DIM);
    float4* xs4 = (float4*)&xs[0][0];
    for (int i = tid; i < rowsHere * IN_DIM / 4; i += 256) xs4[i] = x4[i];
    __syncthreads();

    const int col = tid & 127;   // output column 0..127
    const int sub = tid >> 7;    // 0/1: which row of the pair
    const int h = col >> 5;
    const int f = col & 31;
    const float att_s = atts[h][f];
    const float att_d = atts[h][OUT_DIM + f];

    for (int r = sub; r < rowsHere; r += 2) {
        float acc = 0.f;
#pragma unroll 8
        for (int k = 0; k < IN_DIM; ++k)
            acc = fmaf(xs[r][k], Ws[k][col], acc);  // Ws: 2-way bank alias (free)
        const int row = rowBase + r;
        Wh[(size_t)row * HF + col] = acc;

        // reduce acc*att over f within each 32-lane head segment
        float ps = acc * att_s;
        float pd = acc * att_d;
#pragma unroll
        for (int d = 16; d > 0; d >>= 1) {
            ps += __shfl_down(ps, d, 32);
            pd += __shfl_down(pd, d, 32);
        }
        if (f == 0) {
            a_src[row * HEADS + h] = ps;
            a_dst[row * HEADS + h] = pd;
        }
    }
}

// ---------------------------------------------------------------------------
// Init: out = broadcast(bias), denom = 0   (ws/out are poisoned 0xAA each call)
// ---------------------------------------------------------------------------
__global__ __launch_bounds__(256) void gat_init(
        const float* __restrict__ bias, float* __restrict__ out,
        float* __restrict__ denom) {
    const int i = blockIdx.x * 256 + threadIdx.x;
    if (i < N_NODES * HF) out[i] = bias[i & 127];
    if (i < N_NODES * HEADS) denom[i] = 0.f;
}

// ---------------------------------------------------------------------------
// Edge pass 1: denominators. One thread per edge handles 4 heads.
// No segment-max: logits are bounded (|s| < ~8) so exp() is fp32-safe and
// alpha is mathematically identical to the stabilized form.
// ---------------------------------------------------------------------------
__global__ __launch_bounds__(256) void gat_denom(
        const int* __restrict__ ei, const float* __restrict__ a_src,
        const float* __restrict__ a_dst, float* __restrict__ denom) {
    const int e = blockIdx.x * 256 + threadIdx.x;
    if (e >= E_EDGES) return;
    const int s = ei[e];
    const int d = ei[E_EDGES + e];
    const float4 as = ((const float4*)a_src)[s];
    const float4 ad = ((const float4*)a_dst)[d];
    float v[4] = {as.x + ad.x, as.y + ad.y, as.z + ad.z, as.w + ad.w};
#pragma unroll
    for (int h = 0; h < 4; ++h) {
        float t = v[h];
        t = t > 0.f ? t : NEG_SLOPE * t;
        atomicAdd(&denom[d * 4 + h], __expf(t));
    }
}

// ---------------------------------------------------------------------------
// Edge pass 2: alpha recompute + gather Wh[src] + atomic scatter to out[dst].
// 128 consecutive threads cover one edge's 128 channels (coalesced gather
// and coalesced-address atomics).
// ---------------------------------------------------------------------------
__global__ __launch_bounds__(256) void gat_scatter(
        const int* __restrict__ ei, const float* __restrict__ a_src,
        const float* __restrict__ a_dst, const float* __restrict__ denom,
        const float* __restrict__ Wh, float* __restrict__ out) {
    const unsigned idx = blockIdx.x * 256u + threadIdx.x;  // < E*128 = 204.8M
    const int e = idx >> 7;
    const int c = idx & 127;
    if (e >= E_EDGES) return;
    const int s = ei[e];
    const int d = ei[E_EDGES + e];
    const int h = c >> 5;
    float sc = a_src[s * 4 + h] + a_dst[d * 4 + h];
    sc = sc > 0.f ? sc : NEG_SLOPE * sc;
    const float al = __expf(sc) / fmaxf(denom[d * 4 + h], 1e-9f);
    atomicAdd(&out[(size_t)d * HF + c], al * Wh[(size_t)s * HF + c]);
}

// ---------------------------------------------------------------------------
extern "C" void kernel_launch(void* const* d_in, const int* in_sizes, int n_in,
                              void* d_out, int out_size, void* d_ws, size_t ws_size,
                              hipStream_t stream) {
    const float* x    = (const float*)d_in[0];
    const int*   ei   = (const int*)d_in[1];   // [2, E] int32
    const float* W    = (const float*)d_in[2];
    const float* att  = (const float*)d_in[3];
    const float* bias = (const float*)d_in[4];
    float* out = (float*)d_out;

    // Workspace layout (floats): Wh[N*128] | a_src[N*4] | a_dst[N*4] | denom[N*4]
    float* Wh    = (float*)d_ws;
    float* a_src = Wh + (size_t)N_NODES * HF;
    float* a_dst = a_src + (size_t)N_NODES * HEADS;
    float* denom = a_dst + (size_t)N_NODES * HEADS;

    gat_init<<<(N_NODES * HF + 255) / 256, 256, 0, stream>>>(bias, out, denom);
    gat_proj<<<(N_NODES + 31) / 32, 256, 0, stream>>>(x, W, att, Wh, a_src, a_dst);
    gat_denom<<<(E_EDGES + 255) / 256, 256, 0, stream>>>(ei, a_src, a_dst, denom);
    gat_scatter<<<(E_EDGES * 128) / 256, 256, 0, stream>>>(ei, a_src, a_dst, denom,
                                                           Wh, out);
}

// Round 2
// 541.234 us; speedup vs baseline: 2.3876x; 2.3876x over previous
//
#include <hip/hip_runtime.h>
#include <math.h>

#define N_NODES 50000
#define E_EDGES 1600000
#define IN_DIM 128
#define HEADS 4
#define OUT_DIM 32
#define HF 128            // HEADS*OUT_DIM
#define NEG_SLOPE 0.2f

// ---------------------------------------------------------------------------
// Projection: Wh = x @ W  (N x 128 @ 128 x 128) + fused attention halves.
// Block 256 threads, 64 rows/block. Thread tile: 4 rows x 8 cols (32 acc).
// LDS: Ws 64KB + xs 33KB (padded to 132 to break bank aliasing).
// ---------------------------------------------------------------------------
__global__ __launch_bounds__(256) void gat_proj(
        const float* __restrict__ x, const float* __restrict__ W,
        const float* __restrict__ att, float* __restrict__ Wh,
        float* __restrict__ a_src, float* __restrict__ a_dst) {
    __shared__ float Ws[IN_DIM][HF];        // 64 KB
    __shared__ float xs[64][132];           // 33 KB (pad 132: rows stay 16B-aligned)
    __shared__ float atts[HEADS][2 * OUT_DIM];

    const int tid = threadIdx.x;

    const float4* W4 = (const float4*)W;
    float4* Ws4 = (float4*)&Ws[0][0];
#pragma unroll
    for (int i = 0; i < 16; ++i) Ws4[tid + 256 * i] = W4[tid + 256 * i];
    if (tid < 64) ((float4*)&atts[0][0])[tid] = ((const float4*)att)[tid];

    const int rowBase = blockIdx.x * 64;
    const int rowsHere = min(64, N_NODES - rowBase);
    const float4* x4 = (const float4*)(x + (size_t)rowBase * IN_DIM);
    for (int i = tid; i < rowsHere * 32; i += 256) {
        const int r = i >> 5, q = i & 31;
        *(float4*)&xs[r][q * 4] = x4[i];
    }
    __syncthreads();

    const int rg = tid >> 4;        // 0..15 -> rows rg*4 .. rg*4+3
    const int cg = tid & 15;        // 0..15 -> cols cg*8 .. cg*8+7
    const int r0 = rg * 4;
    const int c0 = cg * 8;
    const int h  = cg >> 2;         // head (8 cols always inside one head)
    const int f0 = (cg & 3) * 8;    // feature offset within head

    float acc[4][8];
#pragma unroll
    for (int i = 0; i < 4; ++i)
#pragma unroll
        for (int j = 0; j < 8; ++j) acc[i][j] = 0.f;

    for (int k = 0; k < IN_DIM; ++k) {
        float a0 = xs[r0 + 0][k], a1 = xs[r0 + 1][k];
        float a2 = xs[r0 + 2][k], a3 = xs[r0 + 3][k];
        float4 w0 = *(const float4*)&Ws[k][c0];
        float4 w1 = *(const float4*)&Ws[k][c0 + 4];
        const float wv[8] = {w0.x, w0.y, w0.z, w0.w, w1.x, w1.y, w1.z, w1.w};
#pragma unroll
        for (int j = 0; j < 8; ++j) {
            acc[0][j] = fmaf(a0, wv[j], acc[0][j]);
            acc[1][j] = fmaf(a1, wv[j], acc[1][j]);
            acc[2][j] = fmaf(a2, wv[j], acc[2][j]);
            acc[3][j] = fmaf(a3, wv[j], acc[3][j]);
        }
    }

#pragma unroll
    for (int i = 0; i < 4; ++i) {
        const int r = r0 + i;
        if (r >= rowsHere) break;
        const int row = rowBase + r;
        float4 s0 = {acc[i][0], acc[i][1], acc[i][2], acc[i][3]};
        float4 s1 = {acc[i][4], acc[i][5], acc[i][6], acc[i][7]};
        float4* o = (float4*)(Wh + (size_t)row * HF + c0);
        o[0] = s0; o[1] = s1;

        float ps = 0.f, pd = 0.f;
#pragma unroll
        for (int j = 0; j < 8; ++j) {
            ps = fmaf(acc[i][j], atts[h][f0 + j], ps);
            pd = fmaf(acc[i][j], atts[h][OUT_DIM + f0 + j], pd);
        }
        // reduce across the 4 lanes (cg&3 = 0..3) sharing (row, head)
        ps += __shfl_xor(ps, 1, 64); ps += __shfl_xor(ps, 2, 64);
        pd += __shfl_xor(pd, 1, 64); pd += __shfl_xor(pd, 2, 64);
        if ((cg & 3) == 0) {
            a_src[row * HEADS + h] = ps;
            a_dst[row * HEADS + h] = pd;
        }
    }
}

// ---------------------------------------------------------------------------
// CSR build: zero counts -> histogram -> single-block scan -> fill
// ---------------------------------------------------------------------------
__global__ __launch_bounds__(256) void gat_zero(int* __restrict__ counts) {
    const int i = blockIdx.x * 256 + threadIdx.x;
    if (i < N_NODES) counts[i] = 0;
}

__global__ __launch_bounds__(256) void gat_hist(
        const int* __restrict__ ei, int* __restrict__ counts) {
    const int e = blockIdx.x * 256 + threadIdx.x;
    if (e >= E_EDGES) return;
    atomicAdd(&counts[ei[E_EDGES + e]], 1);
}

#define SCAN_T 1024
#define CHUNK 49   // ceil(50000/1024)
__global__ __launch_bounds__(SCAN_T) void gat_scan(
        const int* __restrict__ counts, int* __restrict__ offsets,
        int* __restrict__ cursor) {
    __shared__ int part[SCAN_T];
    const int t = threadIdx.x;
    const int lo = t * CHUNK;
    const int hi = min(lo + CHUNK, N_NODES);
    int s = 0;
    for (int i = lo; i < hi; ++i) s += counts[i];
    part[t] = s;
    __syncthreads();
    for (int d = 1; d < SCAN_T; d <<= 1) {
        int v = (t >= d) ? part[t - d] : 0;
        __syncthreads();
        part[t] += v;
        __syncthreads();
    }
    int run = (t == 0) ? 0 : part[t - 1];
    for (int i = lo; i < hi; ++i) {
        offsets[i] = run; cursor[i] = run;
        run += counts[i];
    }
    if (t == SCAN_T - 1) offsets[N_NODES] = run;   // == E
}

__global__ __launch_bounds__(256) void gat_fill(
        const int* __restrict__ ei, int* __restrict__ cursor,
        int* __restrict__ csr_src) {
    const int e = blockIdx.x * 256 + threadIdx.x;
    if (e >= E_EDGES) return;
    const int d = ei[E_EDGES + e];
    const int pos = atomicAdd(&cursor[d], 1);
    csr_src[pos] = ei[e];
}

// ---------------------------------------------------------------------------
// Gather: one 64-lane wave per dst node, float2 per lane = 128 channels.
// Accumulates unnormalized w and w*Wh; divides at the end (denom fused).
// ---------------------------------------------------------------------------
__global__ __launch_bounds__(256) void gat_gather(
        const int* __restrict__ offsets, const int* __restrict__ csr_src,
        const float* __restrict__ a_src, const float* __restrict__ a_dst,
        const float* __restrict__ Wh, const float* __restrict__ bias,
        float* __restrict__ out) {
    const int node = blockIdx.x * 4 + (threadIdx.x >> 6);
    const int lane = threadIdx.x & 63;
    if (node >= N_NODES) return;
    const int h = lane >> 4;                 // channels (2*lane, 2*lane+1) -> head
    const float ad = a_dst[node * HEADS + h];
    const float2* __restrict__ Wh2 = (const float2*)Wh;

    float2 acc = {0.f, 0.f};
    float den = 0.f;
    const int beg = offsets[node];
    const int end = offsets[node + 1];

    int e = beg;
    int s_next = (e < end) ? csr_src[e] : 0;
    while (e < end) {
        const int s = s_next;
        ++e;
        if (e < end) s_next = csr_src[e];     // prefetch next src index
        float t = a_src[s * HEADS + h] + ad;
        t = t > 0.f ? t : NEG_SLOPE * t;
        const float w = __expf(t);
        const float2 v = Wh2[(size_t)s * 64 + lane];
        acc.x = fmaf(w, v.x, acc.x);
        acc.y = fmaf(w, v.y, acc.y);
        den += w;
    }
    const float inv = 1.f / fmaxf(den, 1e-9f);
    const float2 b2 = ((const float2*)bias)[lane];
    float2 o = {acc.x * inv + b2.x, acc.y * inv + b2.y};
    ((float2*)out)[(size_t)node * 64 + lane] = o;
}

// ---------------------------------------------------------------------------
extern "C" void kernel_launch(void* const* d_in, const int* in_sizes, int n_in,
                              void* d_out, int out_size, void* d_ws, size_t ws_size,
                              hipStream_t stream) {
    const float* x    = (const float*)d_in[0];
    const int*   ei   = (const int*)d_in[1];   // [2, E]
    const float* W    = (const float*)d_in[2];
    const float* att  = (const float*)d_in[3];
    const float* bias = (const float*)d_in[4];
    float* out = (float*)d_out;

    // Workspace: Wh[N*128] | a_src[N*4] | a_dst[N*4] | counts[N] | offsets[N+1]
    //            | cursor[N] | csr_src[E]     (~34.2 MB)
    float* Wh      = (float*)d_ws;
    float* a_src   = Wh + (size_t)N_NODES * HF;
    float* a_dst   = a_src + (size_t)N_NODES * HEADS;
    int*   counts  = (int*)(a_dst + (size_t)N_NODES * HEADS);
    int*   offsets = counts + N_NODES;
    int*   cursor  = offsets + N_NODES + 1;
    int*   csr_src = cursor + N_NODES;

    gat_zero<<<(N_NODES + 255) / 256, 256, 0, stream>>>(counts);
    gat_proj<<<(N_NODES + 63) / 64, 256, 0, stream>>>(x, W, att, Wh, a_src, a_dst);
    gat_hist<<<(E_EDGES + 255) / 256, 256, 0, stream>>>(ei, counts);
    gat_scan<<<1, SCAN_T, 0, stream>>>(counts, offsets, cursor);
    gat_fill<<<(E_EDGES + 255) / 256, 256, 0, stream>>>(ei, cursor, csr_src);
    gat_gather<<<(N_NODES + 3) / 4, 256, 0, stream>>>(offsets, csr_src, a_src,
                                                      a_dst, Wh, bias, out);
}

// Round 3
// 429.881 us; speedup vs baseline: 3.0061x; 1.2590x over previous
//
#include <hip/hip_runtime.h>
#include <hip/hip_fp16.h>
#include <math.h>

#define N_NODES 50000
#define E_EDGES 1600000
#define IN_DIM 128
#define HEADS 4
#define OUT_DIM 32
#define HF 128            // HEADS*OUT_DIM
#define NEG_SLOPE 0.2f
#define CPAD 16           // counters padded to one per 64B line

// ---------------------------------------------------------------------------
// Projection: Wh = x @ W  (N x 128 @ 128 x 128) + fused attention halves.
// Wh is stored in fp16 (only consumer is the gather; values are O(1)).
// Block 256 threads, 64 rows/block. Thread tile: 4 rows x 8 cols.
// ---------------------------------------------------------------------------
__global__ __launch_bounds__(256) void gat_proj(
        const float* __restrict__ x, const float* __restrict__ W,
        const float* __restrict__ att, __half* __restrict__ Whh,
        float* __restrict__ a_src, float* __restrict__ a_dst) {
    __shared__ float Ws[IN_DIM][HF];        // 64 KB
    __shared__ float xs[64][132];           // 33 KB (pad: rows stay 16B-aligned)
    __shared__ float atts[HEADS][2 * OUT_DIM];

    const int tid = threadIdx.x;

    const float4* W4 = (const float4*)W;
    float4* Ws4 = (float4*)&Ws[0][0];
#pragma unroll
    for (int i = 0; i < 16; ++i) Ws4[tid + 256 * i] = W4[tid + 256 * i];
    if (tid < 64) ((float4*)&atts[0][0])[tid] = ((const float4*)att)[tid];

    const int rowBase = blockIdx.x * 64;
    const int rowsHere = min(64, N_NODES - rowBase);
    const float4* x4 = (const float4*)(x + (size_t)rowBase * IN_DIM);
    for (int i = tid; i < rowsHere * 32; i += 256) {
        const int r = i >> 5, q = i & 31;
        *(float4*)&xs[r][q * 4] = x4[i];
    }
    __syncthreads();

    const int rg = tid >> 4;        // 0..15 -> rows rg*4 .. rg*4+3
    const int cg = tid & 15;        // 0..15 -> cols cg*8 .. cg*8+7
    const int r0 = rg * 4;
    const int c0 = cg * 8;
    const int h  = cg >> 2;         // head (8 cols always inside one head)
    const int f0 = (cg & 3) * 8;    // feature offset within head

    float acc[4][8];
#pragma unroll
    for (int i = 0; i < 4; ++i)
#pragma unroll
        for (int j = 0; j < 8; ++j) acc[i][j] = 0.f;

    for (int k = 0; k < IN_DIM; ++k) {
        float a0 = xs[r0 + 0][k], a1 = xs[r0 + 1][k];
        float a2 = xs[r0 + 2][k], a3 = xs[r0 + 3][k];
        float4 w0 = *(const float4*)&Ws[k][c0];
        float4 w1 = *(const float4*)&Ws[k][c0 + 4];
        const float wv[8] = {w0.x, w0.y, w0.z, w0.w, w1.x, w1.y, w1.z, w1.w};
#pragma unroll
        for (int j = 0; j < 8; ++j) {
            acc[0][j] = fmaf(a0, wv[j], acc[0][j]);
            acc[1][j] = fmaf(a1, wv[j], acc[1][j]);
            acc[2][j] = fmaf(a2, wv[j], acc[2][j]);
            acc[3][j] = fmaf(a3, wv[j], acc[3][j]);
        }
    }

#pragma unroll
    for (int i = 0; i < 4; ++i) {
        const int r = r0 + i;
        if (r >= rowsHere) break;
        const int row = rowBase + r;
        union { __half2 h[4]; float4 f; } u;
        u.h[0] = __floats2half2_rn(acc[i][0], acc[i][1]);
        u.h[1] = __floats2half2_rn(acc[i][2], acc[i][3]);
        u.h[2] = __floats2half2_rn(acc[i][4], acc[i][5]);
        u.h[3] = __floats2half2_rn(acc[i][6], acc[i][7]);
        *(float4*)(Whh + (size_t)row * HF + c0) = u.f;

        float ps = 0.f, pd = 0.f;
#pragma unroll
        for (int j = 0; j < 8; ++j) {
            ps = fmaf(acc[i][j], atts[h][f0 + j], ps);
            pd = fmaf(acc[i][j], atts[h][OUT_DIM + f0 + j], pd);
        }
        ps += __shfl_xor(ps, 1, 64); ps += __shfl_xor(ps, 2, 64);
        pd += __shfl_xor(pd, 1, 64); pd += __shfl_xor(pd, 2, 64);
        if ((cg & 3) == 0) {
            a_src[row * HEADS + h] = ps;
            a_dst[row * HEADS + h] = pd;
        }
    }
}

// ---------------------------------------------------------------------------
// Pass 1: per-edge rank within its dst segment. Padded counters (1/line)
// kill line-level atomic serialization. 2 edges/thread, coalesced rank store.
// ---------------------------------------------------------------------------
__global__ __launch_bounds__(256) void gat_rank(
        const int* __restrict__ ei, int* __restrict__ counts,
        int* __restrict__ rank) {
    const int t = blockIdx.x * 256 + threadIdx.x;
    if (t >= E_EDGES / 2) return;
    const int2 d2 = ((const int2*)(ei + E_EDGES))[t];
    int2 r2;
    r2.x = atomicAdd(&counts[d2.x * CPAD], 1);
    r2.y = atomicAdd(&counts[d2.y * CPAD], 1);
    ((int2*)rank)[t] = r2;
}

// ---------------------------------------------------------------------------
// Single-block scan of padded counts -> offsets
// ---------------------------------------------------------------------------
#define SCAN_T 1024
#define CHUNK 49   // ceil(50000/1024)
__global__ __launch_bounds__(SCAN_T) void gat_scan(
        const int* __restrict__ counts, int* __restrict__ offsets) {
    __shared__ int part[SCAN_T];
    const int t = threadIdx.x;
    const int lo = t * CHUNK;
    const int hi = min(lo + CHUNK, N_NODES);
    int s = 0;
    for (int i = lo; i < hi; ++i) s += counts[i * CPAD];
    part[t] = s;
    __syncthreads();
    for (int d = 1; d < SCAN_T; d <<= 1) {
        int v = (t >= d) ? part[t - d] : 0;
        __syncthreads();
        part[t] += v;
        __syncthreads();
    }
    int run = (t == 0) ? 0 : part[t - 1];
    for (int i = lo; i < hi; ++i) {
        offsets[i] = run;
        run += counts[i * CPAD];
    }
    if (t == SCAN_T - 1) offsets[N_NODES] = run;   // == E
}

// ---------------------------------------------------------------------------
// Pass 2: atomic-free fill. pos = offsets[dst] + rank[e].
// ---------------------------------------------------------------------------
__global__ __launch_bounds__(256) void gat_fill(
        const int* __restrict__ ei, const int* __restrict__ offsets,
        const int* __restrict__ rank, int* __restrict__ csr_src) {
    const int t = blockIdx.x * 256 + threadIdx.x;
    if (t >= E_EDGES / 2) return;
    const int2 s2 = ((const int2*)ei)[t];
    const int2 d2 = ((const int2*)(ei + E_EDGES))[t];
    const int2 r2 = ((const int2*)rank)[t];
    csr_src[offsets[d2.x] + r2.x] = s2.x;
    csr_src[offsets[d2.y] + r2.y] = s2.y;
}

// ---------------------------------------------------------------------------
// Gather: one 64-lane wave per dst node, half2 per lane = 128 channels.
// Accumulates unnormalized w and w*Wh in fp32; divides at the end.
// ---------------------------------------------------------------------------
__global__ __launch_bounds__(256) void gat_gather(
        const int* __restrict__ offsets, const int* __restrict__ csr_src,
        const float* __restrict__ a_src, const float* __restrict__ a_dst,
        const __half* __restrict__ Whh, const float* __restrict__ bias,
        float* __restrict__ out) {
    const int node = blockIdx.x * 4 + (threadIdx.x >> 6);
    const int lane = threadIdx.x & 63;
    if (node >= N_NODES) return;
    const int h = lane >> 4;                 // channels (2*lane, 2*lane+1)
    const float ad = a_dst[node * HEADS + h];
    const __half2* __restrict__ Wh2 = (const __half2*)Whh;

    float accx = 0.f, accy = 0.f, den = 0.f;
    const int beg = offsets[node];
    const int end = offsets[node + 1];

    int e = beg;
    int s_next = (e < end) ? csr_src[e] : 0;
    while (e < end) {
        const int s = s_next;
        ++e;
        if (e < end) s_next = csr_src[e];     // prefetch next src index
        float t = a_src[s * HEADS + h] + ad;
        t = t > 0.f ? t : NEG_SLOPE * t;
        const float w = __expf(t);
        const float2 v = __half22float2(Wh2[(size_t)s * 64 + lane]);
        accx = fmaf(w, v.x, accx);
        accy = fmaf(w, v.y, accy);
        den += w;
    }
    const float inv = 1.f / fmaxf(den, 1e-9f);
    const float2 b2 = ((const float2*)bias)[lane];
    float2 o = {accx * inv + b2.x, accy * inv + b2.y};
    ((float2*)out)[(size_t)node * 64 + lane] = o;
}

// ---------------------------------------------------------------------------
extern "C" void kernel_launch(void* const* d_in, const int* in_sizes, int n_in,
                              void* d_out, int out_size, void* d_ws, size_t ws_size,
                              hipStream_t stream) {
    const float* x    = (const float*)d_in[0];
    const int*   ei   = (const int*)d_in[1];   // [2, E]
    const float* W    = (const float*)d_in[2];
    const float* att  = (const float*)d_in[3];
    const float* bias = (const float*)d_in[4];
    float* out = (float*)d_out;

    // Workspace: Whh[N*128 half] | a_src[N*4 f32] | a_dst[N*4 f32]
    //            | counts[N*CPAD] | offsets[N+2] | rank[E] | csr_src[E]  (~30.6MB)
    __half* Whh   = (__half*)d_ws;
    float* a_src  = (float*)(Whh + (size_t)N_NODES * HF);
    float* a_dst  = a_src + (size_t)N_NODES * HEADS;
    int*   counts = (int*)(a_dst + (size_t)N_NODES * HEADS);
    int*   offsets = counts + (size_t)N_NODES * CPAD;
    int*   rank    = offsets + N_NODES + 2;   // +2 keeps 8B alignment
    int*   csr_src = rank + E_EDGES;

    hipMemsetAsync(counts, 0, (size_t)N_NODES * CPAD * 4, stream);
    gat_proj<<<(N_NODES + 63) / 64, 256, 0, stream>>>(x, W, att, Whh, a_src, a_dst);
    gat_rank<<<(E_EDGES / 2 + 255) / 256, 256, 0, stream>>>(ei, counts, rank);
    gat_scan<<<1, SCAN_T, 0, stream>>>(counts, offsets);
    gat_fill<<<(E_EDGES / 2 + 255) / 256, 256, 0, stream>>>(ei, offsets, rank, csr_src);
    gat_gather<<<(N_NODES + 3) / 4, 256, 0, stream>>>(offsets, csr_src, a_src,
                                                      a_dst, Whh, bias, out);
}

// Round 4
// 328.677 us; speedup vs baseline: 3.9317x; 1.3079x over previous
//
#include <hip/hip_runtime.h>
#include <hip/hip_fp16.h>
#include <math.h>

#define N_NODES 50000
#define E_EDGES 1600000
#define IN_DIM 128
#define HEADS 4
#define OUT_DIM 32
#define HF 128            // HEADS*OUT_DIM
#define NEG_SLOPE 0.2f
#define CPAD 16           // counters padded to one per 64B line
#define NB 196            // ceil(N_NODES/256) scan blocks

// ---------------------------------------------------------------------------
// Projection: Wh = x @ W  (N x 128 @ 128 x 128) + fused attention halves.
// Wh is stored in fp16 (only consumer is the gather; values are O(1)).
// ---------------------------------------------------------------------------
__global__ __launch_bounds__(256) void gat_proj(
        const float* __restrict__ x, const float* __restrict__ W,
        const float* __restrict__ att, __half* __restrict__ Whh,
        float* __restrict__ a_src, float* __restrict__ a_dst) {
    __shared__ float Ws[IN_DIM][HF];        // 64 KB
    __shared__ float xs[64][132];           // 33 KB (pad: rows stay 16B-aligned)
    __shared__ float atts[HEADS][2 * OUT_DIM];

    const int tid = threadIdx.x;

    const float4* W4 = (const float4*)W;
    float4* Ws4 = (float4*)&Ws[0][0];
#pragma unroll
    for (int i = 0; i < 16; ++i) Ws4[tid + 256 * i] = W4[tid + 256 * i];
    if (tid < 64) ((float4*)&atts[0][0])[tid] = ((const float4*)att)[tid];

    const int rowBase = blockIdx.x * 64;
    const int rowsHere = min(64, N_NODES - rowBase);
    const float4* x4 = (const float4*)(x + (size_t)rowBase * IN_DIM);
    for (int i = tid; i < rowsHere * 32; i += 256) {
        const int r = i >> 5, q = i & 31;
        *(float4*)&xs[r][q * 4] = x4[i];
    }
    __syncthreads();

    const int rg = tid >> 4;
    const int cg = tid & 15;
    const int r0 = rg * 4;
    const int c0 = cg * 8;
    const int h  = cg >> 2;
    const int f0 = (cg & 3) * 8;

    float acc[4][8];
#pragma unroll
    for (int i = 0; i < 4; ++i)
#pragma unroll
        for (int j = 0; j < 8; ++j) acc[i][j] = 0.f;

    for (int k = 0; k < IN_DIM; ++k) {
        float a0 = xs[r0 + 0][k], a1 = xs[r0 + 1][k];
        float a2 = xs[r0 + 2][k], a3 = xs[r0 + 3][k];
        float4 w0 = *(const float4*)&Ws[k][c0];
        float4 w1 = *(const float4*)&Ws[k][c0 + 4];
        const float wv[8] = {w0.x, w0.y, w0.z, w0.w, w1.x, w1.y, w1.z, w1.w};
#pragma unroll
        for (int j = 0; j < 8; ++j) {
            acc[0][j] = fmaf(a0, wv[j], acc[0][j]);
            acc[1][j] = fmaf(a1, wv[j], acc[1][j]);
            acc[2][j] = fmaf(a2, wv[j], acc[2][j]);
            acc[3][j] = fmaf(a3, wv[j], acc[3][j]);
        }
    }

#pragma unroll
    for (int i = 0; i < 4; ++i) {
        const int r = r0 + i;
        if (r >= rowsHere) break;
        const int row = rowBase + r;
        union { __half2 h[4]; float4 f; } u;
        u.h[0] = __floats2half2_rn(acc[i][0], acc[i][1]);
        u.h[1] = __floats2half2_rn(acc[i][2], acc[i][3]);
        u.h[2] = __floats2half2_rn(acc[i][4], acc[i][5]);
        u.h[3] = __floats2half2_rn(acc[i][6], acc[i][7]);
        *(float4*)(Whh + (size_t)row * HF + c0) = u.f;

        float ps = 0.f, pd = 0.f;
#pragma unroll
        for (int j = 0; j < 8; ++j) {
            ps = fmaf(acc[i][j], atts[h][f0 + j], ps);
            pd = fmaf(acc[i][j], atts[h][OUT_DIM + f0 + j], pd);
        }
        ps += __shfl_xor(ps, 1, 64); ps += __shfl_xor(ps, 2, 64);
        pd += __shfl_xor(pd, 1, 64); pd += __shfl_xor(pd, 2, 64);
        if ((cg & 3) == 0) {
            a_src[row * HEADS + h] = ps;
            a_dst[row * HEADS + h] = pd;
        }
    }
}

// ---------------------------------------------------------------------------
// Pass 1: per-edge rank within its dst segment. 4 edges/thread, int4 loads.
// ---------------------------------------------------------------------------
__global__ __launch_bounds__(256) void gat_rank(
        const int* __restrict__ ei, int* __restrict__ counts,
        int* __restrict__ rank) {
    const int t = blockIdx.x * 256 + threadIdx.x;
    if (t >= E_EDGES / 4) return;
    const int4 d4 = ((const int4*)(ei + E_EDGES))[t];
    int4 r4;
    r4.x = atomicAdd(&counts[d4.x * CPAD], 1);
    r4.y = atomicAdd(&counts[d4.y * CPAD], 1);
    r4.z = atomicAdd(&counts[d4.z * CPAD], 1);
    r4.w = atomicAdd(&counts[d4.w * CPAD], 1);
    ((int4*)rank)[t] = r4;
}

// ---------------------------------------------------------------------------
// Parallel 3-phase scan of padded counts -> offsets
// ---------------------------------------------------------------------------
__global__ __launch_bounds__(256) void gat_blocksum(
        const int* __restrict__ counts, int* __restrict__ blockSums) {
    __shared__ int ws[4];
    const int i = blockIdx.x * 256 + threadIdx.x;
    int v = (i < N_NODES) ? counts[i * CPAD] : 0;
#pragma unroll
    for (int d = 32; d > 0; d >>= 1) v += __shfl_down(v, d, 64);
    if ((threadIdx.x & 63) == 0) ws[threadIdx.x >> 6] = v;
    __syncthreads();
    if (threadIdx.x == 0)
        blockSums[blockIdx.x] = ws[0] + ws[1] + ws[2] + ws[3];
}

__global__ __launch_bounds__(256) void gat_scanblocks(
        const int* __restrict__ blockSums, int* __restrict__ blockPre) {
    __shared__ int part[256];
    const int t = threadIdx.x;
    int v = (t < NB) ? blockSums[t] : 0;
    part[t] = v;
    __syncthreads();
#pragma unroll
    for (int d = 1; d < 256; d <<= 1) {
        int u = (t >= d) ? part[t - d] : 0;
        __syncthreads();
        part[t] += u;
        __syncthreads();
    }
    if (t < NB) blockPre[t] = part[t] - v;   // exclusive
}

__global__ __launch_bounds__(256) void gat_offsets(
        const int* __restrict__ counts, const int* __restrict__ blockPre,
        int* __restrict__ offsets) {
    __shared__ int part[256];
    const int t = threadIdx.x;
    const int i = blockIdx.x * 256 + t;
    int v = (i < N_NODES) ? counts[i * CPAD] : 0;
    part[t] = v;
    __syncthreads();
#pragma unroll
    for (int d = 1; d < 256; d <<= 1) {
        int u = (t >= d) ? part[t - d] : 0;
        __syncthreads();
        part[t] += u;
        __syncthreads();
    }
    if (i < N_NODES) offsets[i] = blockPre[blockIdx.x] + part[t] - v;
    if (i == 0) offsets[N_NODES] = E_EDGES;   // total is a known constant
}

// ---------------------------------------------------------------------------
// Pass 2: atomic-free fill. pos = offsets[dst] + rank[e]. 4 edges/thread.
// ---------------------------------------------------------------------------
__global__ __launch_bounds__(256) void gat_fill(
        const int* __restrict__ ei, const int* __restrict__ offsets,
        const int* __restrict__ rank, int* __restrict__ csr_src) {
    const int t = blockIdx.x * 256 + threadIdx.x;
    if (t >= E_EDGES / 4) return;
    const int4 s4 = ((const int4*)ei)[t];
    const int4 d4 = ((const int4*)(ei + E_EDGES))[t];
    const int4 r4 = ((const int4*)rank)[t];
    csr_src[offsets[d4.x] + r4.x] = s4.x;
    csr_src[offsets[d4.y] + r4.y] = s4.y;
    csr_src[offsets[d4.z] + r4.z] = s4.z;
    csr_src[offsets[d4.w] + r4.w] = s4.w;
}

// ---------------------------------------------------------------------------
// Gather: one 64-lane wave per dst node, half2 per lane = 128 channels.
// ---------------------------------------------------------------------------
__global__ __launch_bounds__(256) void gat_gather(
        const int* __restrict__ offsets, const int* __restrict__ csr_src,
        const float* __restrict__ a_src, const float* __restrict__ a_dst,
        const __half* __restrict__ Whh, const float* __restrict__ bias,
        float* __restrict__ out) {
    const int node = blockIdx.x * 4 + (threadIdx.x >> 6);
    const int lane = threadIdx.x & 63;
    if (node >= N_NODES) return;
    const int h = lane >> 4;
    const float ad = a_dst[node * HEADS + h];
    const __half2* __restrict__ Wh2 = (const __half2*)Whh;

    float accx = 0.f, accy = 0.f, den = 0.f;
    const int beg = offsets[node];
    const int end = offsets[node + 1];

    int e = beg;
    int s_next = (e < end) ? csr_src[e] : 0;
    while (e < end) {
        const int s = s_next;
        ++e;
        if (e < end) s_next = csr_src[e];
        float t = a_src[s * HEADS + h] + ad;
        t = t > 0.f ? t : NEG_SLOPE * t;
        const float w = __expf(t);
        const float2 v = __half22float2(Wh2[(size_t)s * 64 + lane]);
        accx = fmaf(w, v.x, accx);
        accy = fmaf(w, v.y, accy);
        den += w;
    }
    const float inv = 1.f / fmaxf(den, 1e-9f);
    const float2 b2 = ((const float2*)bias)[lane];
    float2 o = {accx * inv + b2.x, accy * inv + b2.y};
    ((float2*)out)[(size_t)node * 64 + lane] = o;
}

// ---------------------------------------------------------------------------
extern "C" void kernel_launch(void* const* d_in, const int* in_sizes, int n_in,
                              void* d_out, int out_size, void* d_ws, size_t ws_size,
                              hipStream_t stream) {
    const float* x    = (const float*)d_in[0];
    const int*   ei   = (const int*)d_in[1];   // [2, E]
    const float* W    = (const float*)d_in[2];
    const float* att  = (const float*)d_in[3];
    const float* bias = (const float*)d_in[4];
    float* out = (float*)d_out;

    // Workspace: Whh[N*128 half] | a_src[N*4] | a_dst[N*4] | counts[N*CPAD]
    //            | offsets[N+8] | rank[E] | csr_src[E] | blockSums[NB] | blockPre[NB]
    __half* Whh   = (__half*)d_ws;
    float* a_src  = (float*)(Whh + (size_t)N_NODES * HF);
    float* a_dst  = a_src + (size_t)N_NODES * HEADS;
    int*   counts = (int*)(a_dst + (size_t)N_NODES * HEADS);
    int*   offsets = counts + (size_t)N_NODES * CPAD;
    int*   rank    = offsets + N_NODES + 8;   // keeps 16B alignment for int4
    int*   csr_src = rank + E_EDGES;
    int*   blockSums = csr_src + E_EDGES;
    int*   blockPre  = blockSums + NB;

    hipMemsetAsync(counts, 0, (size_t)N_NODES * CPAD * 4, stream);
    gat_proj<<<(N_NODES + 63) / 64, 256, 0, stream>>>(x, W, att, Whh, a_src, a_dst);
    gat_rank<<<(E_EDGES / 4 + 255) / 256, 256, 0, stream>>>(ei, counts, rank);
    gat_blocksum<<<NB, 256, 0, stream>>>(counts, blockSums);
    gat_scanblocks<<<1, 256, 0, stream>>>(blockSums, blockPre);
    gat_offsets<<<NB, 256, 0, stream>>>(counts, blockPre, offsets);
    gat_fill<<<(E_EDGES / 4 + 255) / 256, 256, 0, stream>>>(ei, offsets, rank, csr_src);
    gat_gather<<<(N_NODES + 3) / 4, 256, 0, stream>>>(offsets, csr_src, a_src,
                                                      a_dst, Whh, bias, out);
}

// Round 5
// 280.281 us; speedup vs baseline: 4.6106x; 1.1727x over previous
//
#include <hip/hip_runtime.h>
#include <hip/hip_fp16.h>
#include <math.h>

#define N_NODES 50000
#define E_EDGES 1600000
#define IN_DIM 128
#define HEADS 4
#define OUT_DIM 32
#define HF 128            // HEADS*OUT_DIM
#define NEG_SLOPE 0.2f
#define CPAD 16           // counters padded to one per 64B line
#define NB 196            // ceil(N_NODES/256) scan blocks

// ---------------------------------------------------------------------------
// Projection: Wh = x @ W  (N x 128 @ 128 x 128) + fused attention halves.
// Wh stored fp16. Block 256, 64 rows/block, 4x8 thread tile.
// x-tile read as float4 chunks (ds_read_b128).
// ---------------------------------------------------------------------------
__global__ __launch_bounds__(256) void gat_proj(
        const float* __restrict__ x, const float* __restrict__ W,
        const float* __restrict__ att, __half* __restrict__ Whh,
        float* __restrict__ a_src, float* __restrict__ a_dst) {
    __shared__ float Ws[IN_DIM][HF];        // 64 KB
    __shared__ float xs[64][132];           // pad 132: float4-aligned rows
    __shared__ float atts[HEADS][2 * OUT_DIM];

    const int tid = threadIdx.x;

    const float4* W4 = (const float4*)W;
    float4* Ws4 = (float4*)&Ws[0][0];
#pragma unroll
    for (int i = 0; i < 16; ++i) Ws4[tid + 256 * i] = W4[tid + 256 * i];
    if (tid < 64) ((float4*)&atts[0][0])[tid] = ((const float4*)att)[tid];

    const int rowBase = blockIdx.x * 64;
    const int rowsHere = min(64, N_NODES - rowBase);
    const float4* x4 = (const float4*)(x + (size_t)rowBase * IN_DIM);
    for (int i = tid; i < rowsHere * 32; i += 256) {
        const int r = i >> 5, q = i & 31;
        *(float4*)&xs[r][q * 4] = x4[i];
    }
    __syncthreads();

    const int rg = tid >> 4;
    const int cg = tid & 15;
    const int r0 = rg * 4;
    const int c0 = cg * 8;
    const int h  = cg >> 2;
    const int f0 = (cg & 3) * 8;

    float acc[4][8];
#pragma unroll
    for (int i = 0; i < 4; ++i)
#pragma unroll
        for (int j = 0; j < 8; ++j) acc[i][j] = 0.f;

    for (int k0 = 0; k0 < IN_DIM; k0 += 4) {
        float4 a4[4];
#pragma unroll
        for (int i = 0; i < 4; ++i) a4[i] = *(const float4*)&xs[r0 + i][k0];
#pragma unroll
        for (int kk = 0; kk < 4; ++kk) {
            float4 w0 = *(const float4*)&Ws[k0 + kk][c0];
            float4 w1 = *(const float4*)&Ws[k0 + kk][c0 + 4];
            const float wv[8] = {w0.x, w0.y, w0.z, w0.w, w1.x, w1.y, w1.z, w1.w};
            const float av[4] = {(&a4[0].x)[kk], (&a4[1].x)[kk],
                                 (&a4[2].x)[kk], (&a4[3].x)[kk]};
#pragma unroll
            for (int j = 0; j < 8; ++j) {
                acc[0][j] = fmaf(av[0], wv[j], acc[0][j]);
                acc[1][j] = fmaf(av[1], wv[j], acc[1][j]);
                acc[2][j] = fmaf(av[2], wv[j], acc[2][j]);
                acc[3][j] = fmaf(av[3], wv[j], acc[3][j]);
            }
        }
    }

#pragma unroll
    for (int i = 0; i < 4; ++i) {
        const int r = r0 + i;
        if (r >= rowsHere) break;
        const int row = rowBase + r;
        union { __half2 h[4]; float4 f; } u;
        u.h[0] = __floats2half2_rn(acc[i][0], acc[i][1]);
        u.h[1] = __floats2half2_rn(acc[i][2], acc[i][3]);
        u.h[2] = __floats2half2_rn(acc[i][4], acc[i][5]);
        u.h[3] = __floats2half2_rn(acc[i][6], acc[i][7]);
        *(float4*)(Whh + (size_t)row * HF + c0) = u.f;

        float ps = 0.f, pd = 0.f;
#pragma unroll
        for (int j = 0; j < 8; ++j) {
            ps = fmaf(acc[i][j], atts[h][f0 + j], ps);
            pd = fmaf(acc[i][j], atts[h][OUT_DIM + f0 + j], pd);
        }
        ps += __shfl_xor(ps, 1, 64); ps += __shfl_xor(ps, 2, 64);
        pd += __shfl_xor(pd, 1, 64); pd += __shfl_xor(pd, 2, 64);
        if ((cg & 3) == 0) {
            a_src[row * HEADS + h] = ps;
            a_dst[row * HEADS + h] = pd;
        }
    }
}

// ---------------------------------------------------------------------------
// Pass 1: per-edge rank within its dst segment. 4 edges/thread, int4 loads.
// ---------------------------------------------------------------------------
__global__ __launch_bounds__(256) void gat_rank(
        const int* __restrict__ ei, int* __restrict__ counts,
        int* __restrict__ rank) {
    const int t = blockIdx.x * 256 + threadIdx.x;
    if (t >= E_EDGES / 4) return;
    const int4 d4 = ((const int4*)(ei + E_EDGES))[t];
    int4 r4;
    r4.x = atomicAdd(&counts[d4.x * CPAD], 1);
    r4.y = atomicAdd(&counts[d4.y * CPAD], 1);
    r4.z = atomicAdd(&counts[d4.z * CPAD], 1);
    r4.w = atomicAdd(&counts[d4.w * CPAD], 1);
    ((int4*)rank)[t] = r4;
}

// ---------------------------------------------------------------------------
// Parallel 3-phase scan of padded counts -> offsets
// ---------------------------------------------------------------------------
__global__ __launch_bounds__(256) void gat_blocksum(
        const int* __restrict__ counts, int* __restrict__ blockSums) {
    __shared__ int ws[4];
    const int i = blockIdx.x * 256 + threadIdx.x;
    int v = (i < N_NODES) ? counts[i * CPAD] : 0;
#pragma unroll
    for (int d = 32; d > 0; d >>= 1) v += __shfl_down(v, d, 64);
    if ((threadIdx.x & 63) == 0) ws[threadIdx.x >> 6] = v;
    __syncthreads();
    if (threadIdx.x == 0)
        blockSums[blockIdx.x] = ws[0] + ws[1] + ws[2] + ws[3];
}

__global__ __launch_bounds__(256) void gat_scanblocks(
        const int* __restrict__ blockSums, int* __restrict__ blockPre) {
    __shared__ int part[256];
    const int t = threadIdx.x;
    int v = (t < NB) ? blockSums[t] : 0;
    part[t] = v;
    __syncthreads();
#pragma unroll
    for (int d = 1; d < 256; d <<= 1) {
        int u = (t >= d) ? part[t - d] : 0;
        __syncthreads();
        part[t] += u;
        __syncthreads();
    }
    if (t < NB) blockPre[t] = part[t] - v;   // exclusive
}

__global__ __launch_bounds__(256) void gat_offsets(
        const int* __restrict__ counts, const int* __restrict__ blockPre,
        int* __restrict__ offsets) {
    __shared__ int part[256];
    const int t = threadIdx.x;
    const int i = blockIdx.x * 256 + t;
    int v = (i < N_NODES) ? counts[i * CPAD] : 0;
    part[t] = v;
    __syncthreads();
#pragma unroll
    for (int d = 1; d < 256; d <<= 1) {
        int u = (t >= d) ? part[t - d] : 0;
        __syncthreads();
        part[t] += u;
        __syncthreads();
    }
    if (i < N_NODES) offsets[i] = blockPre[blockIdx.x] + part[t] - v;
    if (i == 0) offsets[N_NODES] = E_EDGES;   // total is a known constant
}

// ---------------------------------------------------------------------------
// Pass 2: atomic-free fill. pos = offsets[dst] + rank[e]. 4 edges/thread.
// ---------------------------------------------------------------------------
__global__ __launch_bounds__(256) void gat_fill(
        const int* __restrict__ ei, const int* __restrict__ offsets,
        const int* __restrict__ rank, int* __restrict__ csr_src) {
    const int t = blockIdx.x * 256 + threadIdx.x;
    if (t >= E_EDGES / 4) return;
    const int4 s4 = ((const int4*)ei)[t];
    const int4 d4 = ((const int4*)(ei + E_EDGES))[t];
    const int4 r4 = ((const int4*)rank)[t];
    csr_src[offsets[d4.x] + r4.x] = s4.x;
    csr_src[offsets[d4.y] + r4.y] = s4.y;
    csr_src[offsets[d4.z] + r4.z] = s4.z;
    csr_src[offsets[d4.w] + r4.w] = s4.w;
}

// ---------------------------------------------------------------------------
// Gather: one 64-lane wave per dst node, half2 per lane = 128 channels.
// Indices batch-loaded (one coalesced load / 64 edges) and broadcast via
// shfl; edge loop unrolled x4 for memory-level parallelism.
// ---------------------------------------------------------------------------
__global__ __launch_bounds__(256) void gat_gather(
        const int* __restrict__ offsets, const int* __restrict__ csr_src,
        const float* __restrict__ a_src, const float* __restrict__ a_dst,
        const __half* __restrict__ Whh, const float* __restrict__ bias,
        float* __restrict__ out) {
    const int node = blockIdx.x * 4 + (threadIdx.x >> 6);
    const int lane = threadIdx.x & 63;
    if (node >= N_NODES) return;
    const int h = lane >> 4;
    const float ad = a_dst[node * HEADS + h];
    const __half2* __restrict__ Wh2 = (const __half2*)Whh;

    float accx = 0.f, accy = 0.f, den = 0.f;
    const int beg = offsets[node];
    const int end = offsets[node + 1];

    for (int base = beg; base < end; base += 64) {
        const int cnt = min(64, end - base);
        const int idx = (base + lane < end) ? csr_src[base + lane] : 0;
        int j = 0;
        for (; j + 4 <= cnt; j += 4) {
            const int s0 = __shfl(idx, j,     64);
            const int s1 = __shfl(idx, j + 1, 64);
            const int s2 = __shfl(idx, j + 2, 64);
            const int s3 = __shfl(idx, j + 3, 64);
            const float as0 = a_src[s0 * 4 + h];
            const float as1 = a_src[s1 * 4 + h];
            const float as2 = a_src[s2 * 4 + h];
            const float as3 = a_src[s3 * 4 + h];
            const __half2 v0 = Wh2[(size_t)s0 * 64 + lane];
            const __half2 v1 = Wh2[(size_t)s1 * 64 + lane];
            const __half2 v2 = Wh2[(size_t)s2 * 64 + lane];
            const __half2 v3 = Wh2[(size_t)s3 * 64 + lane];
            float t0 = as0 + ad; t0 = fmaxf(t0, NEG_SLOPE * t0);
            float t1 = as1 + ad; t1 = fmaxf(t1, NEG_SLOPE * t1);
            float t2 = as2 + ad; t2 = fmaxf(t2, NEG_SLOPE * t2);
            float t3 = as3 + ad; t3 = fmaxf(t3, NEG_SLOPE * t3);
            const float w0 = __expf(t0), w1 = __expf(t1);
            const float w2 = __expf(t2), w3 = __expf(t3);
            const float2 f0 = __half22float2(v0);
            const float2 f1 = __half22float2(v1);
            const float2 f2 = __half22float2(v2);
            const float2 f3 = __half22float2(v3);
            accx = fmaf(w0, f0.x, accx); accy = fmaf(w0, f0.y, accy);
            accx = fmaf(w1, f1.x, accx); accy = fmaf(w1, f1.y, accy);
            accx = fmaf(w2, f2.x, accx); accy = fmaf(w2, f2.y, accy);
            accx = fmaf(w3, f3.x, accx); accy = fmaf(w3, f3.y, accy);
            den += w0 + w1 + w2 + w3;
        }
        for (; j < cnt; ++j) {
            const int s = __shfl(idx, j, 64);
            float t = a_src[s * 4 + h] + ad;
            t = fmaxf(t, NEG_SLOPE * t);
            const float w = __expf(t);
            const float2 v = __half22float2(Wh2[(size_t)s * 64 + lane]);
            accx = fmaf(w, v.x, accx);
            accy = fmaf(w, v.y, accy);
            den += w;
        }
    }
    const float inv = 1.f / fmaxf(den, 1e-9f);
    const float2 b2 = ((const float2*)bias)[lane];
    float2 o = {accx * inv + b2.x, accy * inv + b2.y};
    ((float2*)out)[(size_t)node * 64 + lane] = o;
}

// ---------------------------------------------------------------------------
extern "C" void kernel_launch(void* const* d_in, const int* in_sizes, int n_in,
                              void* d_out, int out_size, void* d_ws, size_t ws_size,
                              hipStream_t stream) {
    const float* x    = (const float*)d_in[0];
    const int*   ei   = (const int*)d_in[1];   // [2, E]
    const float* W    = (const float*)d_in[2];
    const float* att  = (const float*)d_in[3];
    const float* bias = (const float*)d_in[4];
    float* out = (float*)d_out;

    // Workspace: Whh[N*128 half] | a_src[N*4] | a_dst[N*4] | counts[N*CPAD]
    //            | offsets[N+8] | rank[E] | csr_src[E] | blockSums[NB] | blockPre[NB]
    __half* Whh   = (__half*)d_ws;
    float* a_src  = (float*)(Whh + (size_t)N_NODES * HF);
    float* a_dst  = a_src + (size_t)N_NODES * HEADS;
    int*   counts = (int*)(a_dst + (size_t)N_NODES * HEADS);
    int*   offsets = counts + (size_t)N_NODES * CPAD;
    int*   rank    = offsets + N_NODES + 8;   // keeps 16B alignment for int4
    int*   csr_src = rank + E_EDGES;
    int*   blockSums = csr_src + E_EDGES;
    int*   blockPre  = blockSums + NB;

    hipMemsetAsync(counts, 0, (size_t)N_NODES * CPAD * 4, stream);
    gat_proj<<<(N_NODES + 63) / 64, 256, 0, stream>>>(x, W, att, Whh, a_src, a_dst);
    gat_rank<<<(E_EDGES / 4 + 255) / 256, 256, 0, stream>>>(ei, counts, rank);
    gat_blocksum<<<NB, 256, 0, stream>>>(counts, blockSums);
    gat_scanblocks<<<1, 256, 0, stream>>>(blockSums, blockPre);
    gat_offsets<<<NB, 256, 0, stream>>>(counts, blockPre, offsets);
    gat_fill<<<(E_EDGES / 4 + 255) / 256, 256, 0, stream>>>(ei, offsets, rank, csr_src);
    gat_gather<<<(N_NODES + 3) / 4, 256, 0, stream>>>(offsets, csr_src, a_src,
                                                      a_dst, Whh, bias, out);
}